// Round 2
// baseline (1443.457 us; speedup 1.0000x reference)
//
#include <hip/hip_runtime.h>
#include <hip/hip_fp16.h>
#include <stdint.h>

typedef uint32_t u32;
typedef unsigned int v4u __attribute__((ext_vector_type(4)));

constexpr int CB   = 8192;   // batch
constexpr int CG   = 689;    // genes
constexpr int CL   = 6;      // scanned layers
constexpr int CS   = 2785;   // layer width
constexpr int CSP  = 2816;   // padded width for tables
constexpr int CRS  = 8256;   // row stride (elements) of [S,B] half buffers (breaks 16KB aliasing)
constexpr int KCAP = 128;    // max nnz per column (mean 55.7, sd 7.4 -> +9.8 sigma)

union V16 { v4u u; __half2 h2[4]; };

// ---- build CSC tables for the 6 scanned layers: entry = (j<<16)|fp16(w) ----
__global__ __launch_bounds__(256) void build_main(const float* __restrict__ lm,
                                                  const float* __restrict__ W,
                                                  u32* __restrict__ entries,
                                                  int* __restrict__ cnt)
{
    int i = blockIdx.x * 256 + threadIdx.x;
    const int total = CL * CS * CS;
    if (i >= total) return;
    float m = lm[i];
    if (m != 0.0f) {
        int s = i % CS;
        int r = i / CS;
        int l = r / CS;
        int j = r % CS;
        float w = W[i] * m;
        int col = (l + 1) * CSP + s;            // slot 0 reserved for depth-0
        int pos = atomicAdd(&cnt[col], 1);
        if (pos < KCAP) {
            unsigned short hw = __half_as_ushort(__float2half(w));
            entries[col * KCAP + pos] = ((u32)j << 16) | (u32)hw;
        }
    }
}

// ---- depth-0 table from W0 * lm0 ----
__global__ __launch_bounds__(256) void build0(const float* __restrict__ lm0,
                                              const float* __restrict__ W0,
                                              u32* __restrict__ entries,
                                              int* __restrict__ cnt)
{
    int i = blockIdx.x * 256 + threadIdx.x;
    const int total = CG * CS;
    if (i >= total) return;
    float m = lm0[i];
    if (m != 0.0f) {
        int s = i % CS;
        int j = i / CS;
        float w = W0[i] * m;
        int pos = atomicAdd(&cnt[s], 1);
        if (pos < KCAP) {
            unsigned short hw = __half_as_ushort(__float2half(w));
            entries[s * KCAP + pos] = ((u32)j << 16) | (u32)hw;
        }
    }
}

// ---- x [B,G] fp32 -> xT [G, CRS] fp16 ----
__global__ __launch_bounds__(256) void transpose_x(const float* __restrict__ x,
                                                   __half* __restrict__ xT)
{
    __shared__ float tile[32][33];
    int gx = blockIdx.x * 32;
    int gy = blockIdx.y * 32;
    int tx = threadIdx.x, ty = threadIdx.y;
#pragma unroll
    for (int i = 0; i < 32; i += 8) {
        int g = gx + tx;
        int b = gy + ty + i;
        tile[ty + i][tx] = (g < CG) ? x[(size_t)b * CG + g] : 0.f;
    }
    __syncthreads();
#pragma unroll
    for (int i = 0; i < 32; i += 8) {
        int g = gx + ty + i;
        int b = gy + tx;
        if (g < CG) xT[(size_t)g * CRS + b] = __float2half(tile[tx][ty + i]);
    }
}

// ---- sparse masked-linear: hpre[s, bchunk] = bias[s] + sum_k w_k * src[idx_k, bchunk]
//      plus per-column batch sum / sumsq atomics for BN.
//      grid (8, CS), block 64: XCD k (blockIdx.x%8) touches only batch chunk k -> 2.85MB/XCD in L2.
__global__ __launch_bounds__(64) void gather_k(const __half* __restrict__ src,
                                               __half* __restrict__ dst,
                                               const u32* __restrict__ entries,
                                               const int* __restrict__ cnt,
                                               const float* __restrict__ bias,
                                               float* __restrict__ sumv,
                                               float* __restrict__ sumq,
                                               int boff0)
{
    int s = blockIdx.y;
    int boff = boff0 + blockIdx.x * 512 + threadIdx.x * 8;
    int n = cnt[s];
    if (n > KCAP) n = KCAP;
    const u32* e = entries + s * KCAP;
    float bs = bias[s];
    float acc[8];
#pragma unroll
    for (int j = 0; j < 8; j++) acc[j] = bs;

    int k = 0;
    for (; k + 4 <= n; k += 4) {
        v4u ee = *reinterpret_cast<const v4u*>(e + k);
        u32 evs[4] = {ee.x, ee.y, ee.z, ee.w};
#pragma unroll
        for (int q = 0; q < 4; q++) {
            u32 ev = evs[q];
            int idx = (int)(ev >> 16);
            float w = __half2float(__ushort_as_half((unsigned short)(ev & 0xffffu)));
            V16 v; v.u = *reinterpret_cast<const v4u*>(src + (size_t)idx * CRS + boff);
#pragma unroll
            for (int j = 0; j < 4; j++) {
                float2 f = __half22float2(v.h2[j]);
                acc[2*j]   = fmaf(w, f.x, acc[2*j]);
                acc[2*j+1] = fmaf(w, f.y, acc[2*j+1]);
            }
        }
    }
    for (; k < n; k++) {
        u32 ev = e[k];
        int idx = (int)(ev >> 16);
        float w = __half2float(__ushort_as_half((unsigned short)(ev & 0xffffu)));
        V16 v; v.u = *reinterpret_cast<const v4u*>(src + (size_t)idx * CRS + boff);
#pragma unroll
        for (int j = 0; j < 4; j++) {
            float2 f = __half22float2(v.h2[j]);
            acc[2*j]   = fmaf(w, f.x, acc[2*j]);
            acc[2*j+1] = fmaf(w, f.y, acc[2*j+1]);
        }
    }

    V16 o;
#pragma unroll
    for (int j = 0; j < 4; j++) o.h2[j] = __floats2half2_rn(acc[2*j], acc[2*j+1]);
    __builtin_nontemporal_store(o.u, reinterpret_cast<v4u*>(dst + (size_t)s * CRS + boff));

    float ls = 0.f, lq = 0.f;
#pragma unroll
    for (int j = 0; j < 8; j++) { ls += acc[j]; lq += acc[j] * acc[j]; }
#pragma unroll
    for (int off = 32; off > 0; off >>= 1) {
        ls += __shfl_xor(ls, off);
        lq += __shfl_xor(lq, off);
    }
    if (threadIdx.x == 0) { atomicAdd(&sumv[s], ls); atomicAdd(&sumq[s], lq); }
}

// ---- finalize BN stats + tanh + diagonal skip (in place on h) ----
__global__ __launch_bounds__(256) void bn_act(__half* __restrict__ h,
                                              const __half* __restrict__ prev,
                                              const float* __restrict__ sumv,
                                              const float* __restrict__ sumq,
                                              const float* __restrict__ gamma,
                                              const float* __restrict__ beta,
                                              const float* __restrict__ dlv)
{
    int s = blockIdx.y;
    int boff = blockIdx.x * 2048 + threadIdx.x * 8;
    float mean = sumv[s] * (1.0f / CB);
    float var  = sumq[s] * (1.0f / CB) - mean * mean;
    float rstd = rsqrtf(var + 1e-5f);
    float scale = gamma[s] * rstd;
    float shift = beta[s] - mean * scale;
    size_t base = (size_t)s * CRS + boff;
    V16 v; v.u = *reinterpret_cast<const v4u*>(h + base);
    V16 pv;
    float d = 0.f;
    if (prev) { d = dlv[s]; pv.u = *reinterpret_cast<const v4u*>(prev + base); }
    V16 o;
#pragma unroll
    for (int j = 0; j < 4; j++) {
        float2 f = __half22float2(v.h2[j]);
        float t0 = tanhf(fmaf(f.x, scale, shift));
        float t1 = tanhf(fmaf(f.y, scale, shift));
        if (prev) {
            float2 p = __half22float2(pv.h2[j]);
            t0 = fmaf(d, p.x, t0);
            t1 = fmaf(d, p.y, t1);
        }
        o.h2[j] = __floats2half2_rn(t0, t1);
    }
    *reinterpret_cast<v4u*>(h + base) = o.u;
}

// ---- head: out[b] = sum_s h[s,b]*fasm[s]*w_out[s] + b_out ----
__global__ __launch_bounds__(256) void head_k(const __half* __restrict__ h,
                                              const float* __restrict__ fasm,
                                              const float* __restrict__ wout,
                                              const float* __restrict__ bout,
                                              float* __restrict__ out)
{
    int b = blockIdx.x * 256 + threadIdx.x;
    int seg = blockIdx.y;
    int s0 = seg * 349;
    int s1 = s0 + 349; if (s1 > CS) s1 = CS;
    float acc = (seg == 0) ? bout[0] : 0.f;
    for (int s = s0; s < s1; s++) {
        float wv = fasm[s] * wout[s];          // wave-uniform branch below
        if (wv != 0.f) acc = fmaf(wv, __half2float(h[(size_t)s * CRS + b]), acc);
    }
    atomicAdd(&out[b], acc);
}

extern "C" void kernel_launch(void* const* d_in, const int* in_sizes, int n_in,
                              void* d_out, int out_size, void* d_ws, size_t ws_size,
                              hipStream_t stream)
{
    const float* x    = (const float*)d_in[0];
    const float* lm0  = (const float*)d_in[1];
    const float* lm   = (const float*)d_in[2];
    const float* flm  = (const float*)d_in[3];
    const float* fasm = (const float*)d_in[4];
    const float* W0   = (const float*)d_in[5];
    const float* b0   = (const float*)d_in[6];
    const float* W    = (const float*)d_in[7];
    const float* bb   = (const float*)d_in[8];
    const float* gam  = (const float*)d_in[9];
    const float* bet  = (const float*)d_in[10];
    const float* wout = (const float*)d_in[11];
    const float* bout = (const float*)d_in[12];
    float* out = (float*)d_out;

    // workspace carve (16B-aligned offsets)
    char* ws = (char*)d_ws;
    int*    cnt     = (int*)ws;                         //  7*2816*4      =     78,848
    float*  sumv    = (float*)(ws + 78848);             //  7*2816*4      =     78,848
    float*  sumq    = (float*)(ws + 157696);            //  7*2816*4      =     78,848
    u32*    entries = (u32*)(ws + 236544);              //  7*2816*128*4  = 10,092,544
    __half* xT      = (__half*)(ws + 10329088);         //  689*8256*2    = 11,376,768
    __half* hA      = (__half*)(ws + 21705856);         //  2785*8256*2   = 45,985,920
    __half* hB      = (__half*)(ws + 67691776);         //  end 113,677,696

    (void)hipMemsetAsync(ws, 0, 236544, stream);                                // cnt + sums
    (void)hipMemsetAsync(d_out, 0, (size_t)out_size * sizeof(float), stream);

    { int total = CL * CS * CS; build_main<<<dim3((total + 255) / 256), 256, 0, stream>>>(lm, W, entries, cnt); }
    { int total = CG * CS;      build0   <<<dim3((total + 255) / 256), 256, 0, stream>>>(lm0, W0, entries, cnt); }
    transpose_x<<<dim3(22, 256), dim3(32, 8), 0, stream>>>(x, xT);

    const __half* cur = xT;
    __half* bufs[2] = {hA, hB};
    int which = 0;
    for (int t = 0; t < 7; t++) {
        __half* dst = bufs[which];
        const float* bias = (t == 0) ? b0 : bb + (size_t)(t - 1) * CS;
        for (int half = 0; half < 2; half++) {
            gather_k<<<dim3(8, CS), 64, 0, stream>>>(cur, dst,
                entries + (size_t)t * CSP * KCAP, cnt + t * CSP, bias,
                sumv + t * CSP, sumq + t * CSP, half * 4096);
        }
        bn_act<<<dim3(4, CS), 256, 0, stream>>>(dst, (t == 0) ? nullptr : cur,
            sumv + t * CSP, sumq + t * CSP, gam + (size_t)t * CS, bet + (size_t)t * CS,
            (t == 0) ? nullptr : flm + (size_t)(t - 1) * CS);
        cur = dst;
        which ^= 1;
    }
    head_k<<<dim3(32, 8), 256, 0, stream>>>(cur, fasm, wout, bout, out);
}